// Round 1
// 532.313 us; speedup vs baseline: 1.0221x; 1.0221x over previous
//
#include <hip/hip_runtime.h>

// Problem constants (fixed by setup_inputs)
#define BB   8
#define CC   3
#define HH   224
#define WW   224
#define SS   196
#define DD   768
#define PP   14
#define QQ   14
#define HWSZ (HH * WW)        // 50176
#define KIN  (CC * PP * QQ)   // 588
#define PQ   (PP * QQ)        // 196

// ---------------------------------------------------------------------------
// Kernel 1: block = 2 horizontally-adjacent 16x16 patches (128 threads, 2
// waves). Per-pixel argmax over S (float4 over 4 pixels/thread, per-wave
// loads are 8x128B segments = full L2 lines), then accumulate per-(label,ch)
// sums in LDS via LDS atomics, and PLAIN-STORE the block's exclusive
// pooled[b, :, :, p, q0..q0+1] slice. No global atomics, no pooled memset
// (every cell written exactly once). Presence recorded per-block into
// pres2[b, pq, s] (contention-free, coalesced) instead of hammering a shared
// 6KB presence array from all 8 XCDs.
// ---------------------------------------------------------------------------
__global__ __launch_bounds__(128) void k_argmax_pool(
    const float* __restrict__ seg, const float* __restrict__ img,
    float* __restrict__ pooled, int* __restrict__ pres2)
{
    const int b   = blockIdx.y;
    const int p   = blockIdx.x / 7;          // patch row
    const int q0  = (blockIdx.x % 7) * 2;    // first of 2 patch cols
    const int tid = threadIdx.x;
    const int r   = tid >> 3;                // 0..15  (row within patch)
    const int c4  = tid & 7;                 // 0..7   (float4 col across 32px)
    const int pat = c4 >> 2;                 // which of the 2 patches

    const int h = p * 16 + r;
    const int w = q0 * 16 + c4 * 4;
    const int f = h * WW + w;

    __shared__ float accf[2 * SS * 3];       // per-patch, per-label, per-ch
    __shared__ int   flag[2 * SS];
    for (int i = tid; i < 2 * SS * 3; i += 128) accf[i] = 0.f;
    for (int i = tid; i < 2 * SS;     i += 128) flag[i] = 0;
    __syncthreads();

    // ---- per-pixel argmax over S segment logits (4 pixels via float4) ----
    const float4* sp = (const float4*)(seg + (long)b * SS * HWSZ + f);
    const int str4 = HWSZ / 4;

    float4 m = sp[0];
    int lx = 0, ly = 0, lz = 0, lw = 0;
    #pragma unroll 8
    for (int s = 1; s < SS; ++s) {
        float4 v = sp[(size_t)s * str4];
        if (v.x > m.x) { m.x = v.x; lx = s; }
        if (v.y > m.y) { m.y = v.y; ly = s; }
        if (v.z > m.z) { m.z = v.z; lz = s; }
        if (v.w > m.w) { m.w = v.w; lw = s; }
    }

    float4 i0 = *(const float4*)(img + ((long)(b * CC + 0)) * HWSZ + f);
    float4 i1 = *(const float4*)(img + ((long)(b * CC + 1)) * HWSZ + f);
    float4 i2 = *(const float4*)(img + ((long)(b * CC + 2)) * HWSZ + f);

    int   labs[4]   = { lx, ly, lz, lw };
    float imv[4][3] = { { i0.x, i1.x, i2.x }, { i0.y, i1.y, i2.y },
                        { i0.z, i1.z, i2.z }, { i0.w, i1.w, i2.w } };

    float* accp = accf + pat * SS * 3;
    int*   flp  = flag + pat * SS;
    #pragma unroll
    for (int j = 0; j < 4; ++j) {
        int lab = labs[j];
        atomicAdd(&accp[lab * 3 + 0], imv[j][0]);   // LDS atomic (ds_add_f32)
        atomicAdd(&accp[lab * 3 + 1], imv[j][1]);
        atomicAdd(&accp[lab * 3 + 2], imv[j][2]);
        flp[lab] = 1;                               // benign race
    }
    __syncthreads();

    // ---- flush: exclusive owner of pooled[b, :, :, p, q0+pt] -> plain store
    for (int ss = tid; ss < 2 * SS; ss += 128) {
        int pt = ss >= SS;
        int s  = ss - pt * SS;
        int q  = q0 + pt;
        long base = (long)(b * SS + s) * KIN + p * QQ + q;
        const float* a = accf + (pt * SS + s) * 3;
        pooled[base]          = a[0] * (1.0f / 256.0f);
        pooled[base + PQ]     = a[1] * (1.0f / 256.0f);
        pooled[base + 2 * PQ] = a[2] * (1.0f / 256.0f);
        pres2[((long)b * PQ + p * QQ + q) * SS + s] = flag[pt * SS + s];
    }
}

// ---------------------------------------------------------------------------
// Kernel 2: per-batch compaction positions. presence[b,s] = OR over the 196
// patch flags (coalesced 256B reads, all L2-resident), then Hillis-Steele
// scan over 256 slots. pos[b,s] = cumsum(present)-1 if present else -1.
// ---------------------------------------------------------------------------
__global__ __launch_bounds__(256) void k_pos(
    const int* __restrict__ pres2, int* __restrict__ pos)
{
    int b = blockIdx.x;
    int s = threadIdx.x;

    int pres = 0;
    if (s < SS) {
        const int* pp = pres2 + (long)b * PQ * SS + s;
        #pragma unroll 4
        for (int pq = 0; pq < PQ; ++pq) pres |= pp[(long)pq * SS];
    }
    pres = pres ? 1 : 0;

    __shared__ int sc[256];
    sc[s] = pres;
    __syncthreads();

    for (int off = 1; off < 256; off <<= 1) {
        int v = (s >= off) ? sc[s - off] : 0;
        __syncthreads();
        sc[s] += v;
        __syncthreads();
    }
    if (s < SS) pos[b * SS + s] = pres ? (sc[s] - 1) : -1;
}

// ---------------------------------------------------------------------------
// Kernel 3: projection GEMM with scatter-store. NO LDS. (unchanged)
// pooled viewed as [1568, 588]; out[b, pos[b,s], :] = pooled[b,s,:] @ W + bias
// Block = 256 threads, tile = 8 rows x 256 cols; grid (196, 3).
// A addresses are wave-uniform -> s_load_dwordx4 through scalar cache.
// ---------------------------------------------------------------------------
__global__ __launch_bounds__(256) void k_gemm(
    const float* __restrict__ pooled, const float* __restrict__ wp,
    const float* __restrict__ bp, const int* __restrict__ pos,
    float* __restrict__ out)
{
    int row0 = blockIdx.x * 8;                    // 196 row-tiles (exact: 1568/8)
    int d    = threadIdx.x + blockIdx.y * 256;    // output column

    const float* A = pooled + (long)row0 * KIN;

    float acc[8] = {0.f, 0.f, 0.f, 0.f, 0.f, 0.f, 0.f, 0.f};

    #pragma unroll 2
    for (int k4 = 0; k4 < KIN / 4; ++k4) {
        int kb = k4 * 4;
        float w0 = wp[(long)(kb + 0) * DD + d];
        float w1 = wp[(long)(kb + 1) * DD + d];
        float w2 = wp[(long)(kb + 2) * DD + d];
        float w3 = wp[(long)(kb + 3) * DD + d];
        #pragma unroll
        for (int r = 0; r < 8; ++r) {
            float4 a = *(const float4*)(A + (long)r * KIN + kb); // wave-uniform
            acc[r] += a.x * w0;
            acc[r] += a.y * w1;
            acc[r] += a.z * w2;
            acc[r] += a.w * w3;
        }
    }

    float bias = bp[d];
    #pragma unroll
    for (int r = 0; r < 8; ++r) {
        int row = row0 + r;
        int p   = pos[row];
        if (p >= 0) {
            int b = row / SS;
            out[((long)(b * SS + p)) * DD + d] = acc[r] + bias;
        }
    }
}

// ---------------------------------------------------------------------------
extern "C" void kernel_launch(void* const* d_in, const int* in_sizes, int n_in,
                              void* d_out, int out_size, void* d_ws, size_t ws_size,
                              hipStream_t stream) {
    const float* img  = (const float*)d_in[0];   // [8,3,224,224]
    const float* seg  = (const float*)d_in[1];   // [8,196,224,224]
    const float* wp   = (const float*)d_in[2];   // [588,768]
    const float* bp   = (const float*)d_in[3];   // [768]
    float* out = (float*)d_out;                  // [8,196,768]

    // Workspace layout (all regions fully overwritten by k1/k_pos -> no ws memset)
    const size_t pooled_bytes = (size_t)BB * SS * KIN * sizeof(float); // 3,687,936
    const size_t pres2_bytes  = (size_t)BB * PQ * SS * sizeof(int);    // 1,229,312
    float* pooled = (float*)d_ws;
    int*   pres2  = (int*)((char*)d_ws + pooled_bytes);
    int*   pos    = (int*)((char*)d_ws + pooled_bytes + pres2_bytes);

    // Only the output needs zeroing (absent/tail rows must be 0)
    hipMemsetAsync(d_out, 0, (size_t)out_size * sizeof(float), stream);

    // 1) argmax + patch-pool into exclusive pooled slices (no global atomics)
    {
        dim3 grid(PP * 7, BB);                    // (98, 8) = 784 blocks, 2 waves each
        k_argmax_pool<<<grid, 128, 0, stream>>>(seg, img, pooled, pres2);
    }

    // 2) presence OR-reduce + compaction positions
    k_pos<<<dim3(BB), 256, 0, stream>>>(pres2, pos);

    // 3) projection GEMM + scatter store (no LDS)
    {
        dim3 grid(SS * BB / 8, DD / 256);         // (196, 3) = 588 blocks
        k_gemm<<<grid, 256, 0, stream>>>(pooled, wp, bp, pos, out);
    }
}

// Round 2
// 528.128 us; speedup vs baseline: 1.0302x; 1.0079x over previous
//
#include <hip/hip_runtime.h>

// Problem constants (fixed by setup_inputs)
#define BB   8
#define CC   3
#define HH   224
#define WW   224
#define SS   196
#define DD   768
#define PP   14
#define QQ   14
#define HWSZ (HH * WW)        // 50176
#define KIN  (CC * PP * QQ)   // 588
#define PQ   (PP * QQ)        // 196

// ---------------------------------------------------------------------------
// Kernel 1: block = 2 horizontally-adjacent 16x16 patches (128 threads, 2
// waves). Per-pixel argmax over S (float4 over 4 pixels/thread, per-wave
// loads are 8x128B segments = full L2 lines), then accumulate per-(label,ch)
// sums in LDS via LDS atomics, and PLAIN-STORE the block's exclusive
// pooled[b, :, :, p, q0..q0+1] slice. No global atomics, no pooled memset
// (every cell written exactly once). Presence recorded per-block into
// pres2[b, pq, s] (contention-free, coalesced).
// ---------------------------------------------------------------------------
__global__ __launch_bounds__(128) void k_argmax_pool(
    const float* __restrict__ seg, const float* __restrict__ img,
    float* __restrict__ pooled, int* __restrict__ pres2)
{
    const int b   = blockIdx.y;
    const int p   = blockIdx.x / 7;          // patch row
    const int q0  = (blockIdx.x % 7) * 2;    // first of 2 patch cols
    const int tid = threadIdx.x;
    const int r   = tid >> 3;                // 0..15  (row within patch)
    const int c4  = tid & 7;                 // 0..7   (float4 col across 32px)
    const int pat = c4 >> 2;                 // which of the 2 patches

    const int h = p * 16 + r;
    const int w = q0 * 16 + c4 * 4;
    const int f = h * WW + w;

    __shared__ float accf[2 * SS * 3];       // per-patch, per-label, per-ch
    __shared__ int   flag[2 * SS];
    for (int i = tid; i < 2 * SS * 3; i += 128) accf[i] = 0.f;
    for (int i = tid; i < 2 * SS;     i += 128) flag[i] = 0;
    __syncthreads();

    // ---- per-pixel argmax over S segment logits (4 pixels via float4) ----
    const float4* sp = (const float4*)(seg + (long)b * SS * HWSZ + f);
    const int str4 = HWSZ / 4;

    float4 m = sp[0];
    int lx = 0, ly = 0, lz = 0, lw = 0;
    #pragma unroll 8
    for (int s = 1; s < SS; ++s) {
        float4 v = sp[(size_t)s * str4];
        if (v.x > m.x) { m.x = v.x; lx = s; }
        if (v.y > m.y) { m.y = v.y; ly = s; }
        if (v.z > m.z) { m.z = v.z; lz = s; }
        if (v.w > m.w) { m.w = v.w; lw = s; }
    }

    float4 i0 = *(const float4*)(img + ((long)(b * CC + 0)) * HWSZ + f);
    float4 i1 = *(const float4*)(img + ((long)(b * CC + 1)) * HWSZ + f);
    float4 i2 = *(const float4*)(img + ((long)(b * CC + 2)) * HWSZ + f);

    int   labs[4]   = { lx, ly, lz, lw };
    float imv[4][3] = { { i0.x, i1.x, i2.x }, { i0.y, i1.y, i2.y },
                        { i0.z, i1.z, i2.z }, { i0.w, i1.w, i2.w } };

    float* accp = accf + pat * SS * 3;
    int*   flp  = flag + pat * SS;
    #pragma unroll
    for (int j = 0; j < 4; ++j) {
        int lab = labs[j];
        atomicAdd(&accp[lab * 3 + 0], imv[j][0]);   // LDS atomic (ds_add_f32)
        atomicAdd(&accp[lab * 3 + 1], imv[j][1]);
        atomicAdd(&accp[lab * 3 + 2], imv[j][2]);
        flp[lab] = 1;                               // benign race
    }
    __syncthreads();

    // ---- flush: exclusive owner of pooled[b, :, :, p, q0+pt] -> plain store
    for (int ss = tid; ss < 2 * SS; ss += 128) {
        int pt = ss >= SS;
        int s  = ss - pt * SS;
        int q  = q0 + pt;
        long base = (long)(b * SS + s) * KIN + p * QQ + q;
        const float* a = accf + (pt * SS + s) * 3;
        pooled[base]          = a[0] * (1.0f / 256.0f);
        pooled[base + PQ]     = a[1] * (1.0f / 256.0f);
        pooled[base + 2 * PQ] = a[2] * (1.0f / 256.0f);
        pres2[((long)b * PQ + p * QQ + q) * SS + s] = flag[pt * SS + s];
    }
}

// ---------------------------------------------------------------------------
// Kernel 2: per-batch compaction positions, DUAL scan. presence[b,s] = OR
// over the 196 patch flags (coalesced, L2-resident), then one Hillis-Steele
// scan over the present flags. Present segment s -> slot scP(s)-1 (rank among
// present, sorted by s). Absent segment s -> tail slot n + (s - scP(s)),
// encoded as ~slot (negative). Every slot 0..SS-1 is assigned exactly once
// per batch, so k_gemm can write ALL output rows and the d_out memset dies.
// ---------------------------------------------------------------------------
__global__ __launch_bounds__(256) void k_pos(
    const int* __restrict__ pres2, int* __restrict__ pos)
{
    int b = blockIdx.x;
    int s = threadIdx.x;

    int pres = 0;
    if (s < SS) {
        const int* pp = pres2 + (long)b * PQ * SS + s;
        #pragma unroll 4
        for (int pq = 0; pq < PQ; ++pq) pres |= pp[(long)pq * SS];
    }
    pres = pres ? 1 : 0;

    __shared__ int sc[256];
    sc[s] = pres;
    __syncthreads();

    for (int off = 1; off < 256; off <<= 1) {
        int v = (s >= off) ? sc[s - off] : 0;
        __syncthreads();
        sc[s] += v;
        __syncthreads();
    }
    // sc[s] = inclusive prefix sum of present over [0..s]; sc[255] = n total
    if (s < SS) {
        int n = sc[255];
        int slot = pres ? (sc[s] - 1)            // rank among present
                        : (n + s - sc[s]);       // n + rank among absent
        pos[b * SS + s] = pres ? slot : ~slot;   // absent encoded negative
    }
}

// ---------------------------------------------------------------------------
// Kernel 3: projection GEMM with FULL-COVERAGE scatter-store. NO LDS.
// pooled viewed as [1568, 588]; present rows write acc+bias at slot pos,
// absent rows write 0.0f at their tail slot (~pos). Every out[b, slot, :]
// is written exactly once -> no d_out memset needed.
// A addresses are wave-uniform -> s_load_dwordx4 through scalar cache.
// ---------------------------------------------------------------------------
__global__ __launch_bounds__(256) void k_gemm(
    const float* __restrict__ pooled, const float* __restrict__ wp,
    const float* __restrict__ bp, const int* __restrict__ pos,
    float* __restrict__ out)
{
    int row0 = blockIdx.x * 8;                    // 196 row-tiles (exact: 1568/8)
    int d    = threadIdx.x + blockIdx.y * 256;    // output column

    const float* A = pooled + (long)row0 * KIN;

    float acc[8] = {0.f, 0.f, 0.f, 0.f, 0.f, 0.f, 0.f, 0.f};

    #pragma unroll 2
    for (int k4 = 0; k4 < KIN / 4; ++k4) {
        int kb = k4 * 4;
        float w0 = wp[(long)(kb + 0) * DD + d];
        float w1 = wp[(long)(kb + 1) * DD + d];
        float w2 = wp[(long)(kb + 2) * DD + d];
        float w3 = wp[(long)(kb + 3) * DD + d];
        #pragma unroll
        for (int r = 0; r < 8; ++r) {
            float4 a = *(const float4*)(A + (long)r * KIN + kb); // wave-uniform
            acc[r] += a.x * w0;
            acc[r] += a.y * w1;
            acc[r] += a.z * w2;
            acc[r] += a.w * w3;
        }
    }

    float bias = bp[d];
    #pragma unroll
    for (int r = 0; r < 8; ++r) {
        int row = row0 + r;
        int p   = pos[row];
        int b   = row / SS;
        int present = (p >= 0);
        int slot = present ? p : ~p;
        float v  = present ? (acc[r] + bias) : 0.0f;
        out[((long)(b * SS + slot)) * DD + d] = v;
    }
}

// ---------------------------------------------------------------------------
extern "C" void kernel_launch(void* const* d_in, const int* in_sizes, int n_in,
                              void* d_out, int out_size, void* d_ws, size_t ws_size,
                              hipStream_t stream) {
    const float* img  = (const float*)d_in[0];   // [8,3,224,224]
    const float* seg  = (const float*)d_in[1];   // [8,196,224,224]
    const float* wp   = (const float*)d_in[2];   // [588,768]
    const float* bp   = (const float*)d_in[3];   // [768]
    float* out = (float*)d_out;                  // [8,196,768]

    // Workspace layout (all regions fully overwritten by k1/k_pos -> no memsets)
    const size_t pooled_bytes = (size_t)BB * SS * KIN * sizeof(float); // 3,687,936
    const size_t pres2_bytes  = (size_t)BB * PQ * SS * sizeof(int);    // 1,229,312
    float* pooled = (float*)d_ws;
    int*   pres2  = (int*)((char*)d_ws + pooled_bytes);
    int*   pos    = (int*)((char*)d_ws + pooled_bytes + pres2_bytes);

    // 1) argmax + patch-pool into exclusive pooled slices (no global atomics)
    {
        dim3 grid(PP * 7, BB);                    // (98, 8) = 784 blocks, 2 waves each
        k_argmax_pool<<<grid, 128, 0, stream>>>(seg, img, pooled, pres2);
    }

    // 2) presence OR-reduce + dual compaction positions (present/absent slots)
    k_pos<<<dim3(BB), 256, 0, stream>>>(pres2, pos);

    // 3) projection GEMM + full-coverage scatter store (replaces out memset)
    {
        dim3 grid(SS * BB / 8, DD / 256);         // (196, 3) = 588 blocks
        k_gemm<<<grid, 256, 0, stream>>>(pooled, wp, bp, pos, out);
    }
}